// Round 1
// baseline (470.087 us; speedup 1.0000x reference)
//
#include <hip/hip_runtime.h>

#define EPSF 1e-5f

__device__ __forceinline__ float dot4(float4 a, float4 b) {
    return a.x*b.x + a.y*b.y + a.z*b.z + a.w*b.w;
}

// ---------------------------------------------------------------------------
// Kernel 1: fused LayerNorm + projection
// clip_feat [B,768,24,24] -> proj [B,576,256] (fp32, in workspace)
// Block = 256 threads, 32 tokens. Grid = B * 18 = 144.
// ---------------------------------------------------------------------------
__global__ __launch_bounds__(256) void ln_proj_kernel(
    const float* __restrict__ clip,
    const float* __restrict__ gamma,
    const float* __restrict__ beta,
    const float* __restrict__ W,      // [256, 768]
    const float* __restrict__ bias,   // [256]
    float* __restrict__ proj)         // [B, 576, 256]
{
    __shared__ float xs[32][772];     // stride 772: 16B-aligned rows, 4-way max conflicts
    __shared__ float red1[8][32];
    __shared__ float red2[8][32];
    __shared__ float mu_s[32], rs_s[32];

    const int tid = threadIdx.x;
    const int b  = blockIdx.x / 18;
    const int n0 = (blockIdx.x % 18) * 32;
    const int nl = tid & 31;   // token within tile
    const int cg = tid >> 5;   // 0..7

    const float* cf = clip + (size_t)b * 768 * 576;

    // ---- stage raw token data + accumulate mean/var partials ----
    float s1 = 0.f, s2 = 0.f;
    #pragma unroll 4
    for (int i = 0; i < 96; ++i) {
        int c = cg + (i << 3);                    // thread covers c = cg + 8i
        float v = cf[c * 576 + n0 + nl];          // lanes -> consecutive n: coalesced
        xs[nl][c] = v;
        s1 += v; s2 += v * v;
    }
    red1[cg][nl] = s1;
    red2[cg][nl] = s2;
    __syncthreads();
    if (tid < 32) {
        float a = 0.f, q = 0.f;
        #pragma unroll
        for (int g = 0; g < 8; ++g) { a += red1[g][tid]; q += red2[g][tid]; }
        float mu  = a * (1.f / 768.f);
        float var = q * (1.f / 768.f) - mu * mu;
        mu_s[tid] = mu;
        rs_s[tid] = rsqrtf(var + EPSF);
    }
    __syncthreads();

    // ---- normalize in place ----
    {
        float mu = mu_s[nl], rsg = rs_s[nl];
        #pragma unroll 4
        for (int i = 0; i < 96; ++i) {
            int c = cg + (i << 3);
            xs[nl][c] = (xs[nl][c] - mu) * rsg * gamma[c] + beta[c];
        }
    }
    __syncthreads();

    // ---- GEMM: per thread 2 d-columns x 16 tokens ----
    const int dg = tid & 127;          // 0..127
    const int ng = tid >> 7;           // 0..1
    const int d0 = dg * 2, d1 = d0 + 1;
    const float* w0 = W + (size_t)d0 * 768;
    const float* w1 = W + (size_t)d1 * 768;

    float acc0[16], acc1[16];
    #pragma unroll
    for (int j = 0; j < 16; ++j) { acc0[j] = 0.f; acc1[j] = 0.f; }

    for (int k = 0; k < 768; k += 4) {
        float4 a  = *reinterpret_cast<const float4*>(w0 + k);
        float4 b4 = *reinterpret_cast<const float4*>(w1 + k);
        #pragma unroll
        for (int j = 0; j < 16; ++j) {
            float4 x = *reinterpret_cast<const float4*>(&xs[ng * 16 + j][k]); // wave-broadcast
            acc0[j] += dot4(x, a);
            acc1[j] += dot4(x, b4);
        }
    }

    float bb0 = bias[d0], bb1 = bias[d1];
    #pragma unroll
    for (int j = 0; j < 16; ++j) {
        int n = n0 + ng * 16 + j;
        float2 st;
        st.x = acc0[j] + bb0;
        st.y = acc1[j] + bb1;
        *reinterpret_cast<float2*>(&proj[((size_t)b * 576 + n) * 256 + d0]) = st;
    }
}

// ---------------------------------------------------------------------------
// Kernel 2: flash attention  Q=rs_flat [4096,256], K=V=proj [576,256] per batch
// out[b,d,m] = rs[b,d,m] + alpha * (softmax(Q K^T) V)[m,d]
// Block = 256 threads handles 64 Q rows. Grid = B * 64 = 512.
// ---------------------------------------------------------------------------
__global__ __launch_bounds__(256) void attn_kernel(
    const float* __restrict__ proj,    // [B,576,256]
    const float* __restrict__ rs,      // [B,256,4096]
    const float* __restrict__ alpha_p, // [1]
    float* __restrict__ out)           // [B,256,4096]
{
    __shared__ float Qs[64][260];      // 66.6 KB
    __shared__ float Ks[64][260];      // 66.6 KB (doubles as V)
    __shared__ float Ps[64][68];       // 17.4 KB

    const int tid = threadIdx.x;
    const int b  = blockIdx.x >> 6;
    const int q0 = (blockIdx.x & 63) << 6;
    const int tx = tid & 15;           // 0..15
    const int ty = tid >> 4;           // 0..15  (0..3 within a wave)

    // ---- load Q tile [64 m][256 d] (coalesced over m) ----
    {
        int m = tid & 63;
        int dbase = tid >> 6;          // 0..3
        #pragma unroll 4
        for (int i = 0; i < 64; ++i) {
            int d = i * 4 + dbase;
            Qs[m][d] = rs[((size_t)(b * 256 + d)) * 4096 + q0 + m];
        }
    }

    float acc[4][16];
    float mrun[4], lrun[4];
    #pragma unroll
    for (int qi = 0; qi < 4; ++qi) {
        mrun[qi] = -1e30f; lrun[qi] = 0.f;
        #pragma unroll
        for (int j = 0; j < 16; ++j) acc[qi][j] = 0.f;
    }

    for (int kc = 0; kc < 9; ++kc) {
        __syncthreads();               // protects Ks reuse from previous iter
        // ---- load K/V chunk [64 kv][256 d] (coalesced over d) ----
        const float* kp = proj + ((size_t)(b * 576 + kc * 64)) * 256;
        #pragma unroll 4
        for (int i = 0; i < 64; ++i) {
            Ks[i][tid] = kp[i * 256 + tid];
        }
        __syncthreads();

        // ---- S = Q K^T : per thread 4q x 4kv, q = ty+16qi, kv = tx+16kj ----
        float s[4][4];
        #pragma unroll
        for (int qi = 0; qi < 4; ++qi)
            #pragma unroll
            for (int kj = 0; kj < 4; ++kj) s[qi][kj] = 0.f;

        for (int k = 0; k < 256; k += 4) {
            float4 qv[4], kv[4];
            #pragma unroll
            for (int qi = 0; qi < 4; ++qi)
                qv[qi] = *reinterpret_cast<const float4*>(&Qs[ty + 16 * qi][k]);
            #pragma unroll
            for (int kj = 0; kj < 4; ++kj)
                kv[kj] = *reinterpret_cast<const float4*>(&Ks[tx + 16 * kj][k]);
            #pragma unroll
            for (int qi = 0; qi < 4; ++qi)
                #pragma unroll
                for (int kj = 0; kj < 4; ++kj)
                    s[qi][kj] += dot4(qv[qi], kv[kj]);
        }

        // ---- online softmax over kv (reduce across the 16 tx lanes) ----
        #pragma unroll
        for (int qi = 0; qi < 4; ++qi) {
            float mx = fmaxf(fmaxf(s[qi][0], s[qi][1]), fmaxf(s[qi][2], s[qi][3]));
            #pragma unroll
            for (int off = 1; off < 16; off <<= 1)
                mx = fmaxf(mx, __shfl_xor(mx, off, 16));
            float mnew  = fmaxf(mrun[qi], mx);
            float scale = __expf(mrun[qi] - mnew);
            float p[4];
            float rsum = 0.f;
            #pragma unroll
            for (int kj = 0; kj < 4; ++kj) {
                p[kj] = __expf(s[qi][kj] - mnew);
                rsum += p[kj];
            }
            #pragma unroll
            for (int off = 1; off < 16; off <<= 1)
                rsum += __shfl_xor(rsum, off, 16);
            lrun[qi] = lrun[qi] * scale + rsum;
            mrun[qi] = mnew;
            #pragma unroll
            for (int j = 0; j < 16; ++j) acc[qi][j] *= scale;
            #pragma unroll
            for (int kj = 0; kj < 4; ++kj)
                Ps[ty + 16 * qi][tx + 16 * kj] = p[kj];
        }
        __syncthreads();

        // ---- O += P * V : per thread 4q x 16d, d = tx*4 + 64j ----
        for (int kv = 0; kv < 64; ++kv) {
            float pr[4];
            #pragma unroll
            for (int qi = 0; qi < 4; ++qi) pr[qi] = Ps[ty + 16 * qi][kv];
            #pragma unroll
            for (int j = 0; j < 4; ++j) {
                float4 v = *reinterpret_cast<const float4*>(&Ks[kv][tx * 4 + 64 * j]);
                #pragma unroll
                for (int qi = 0; qi < 4; ++qi) {
                    acc[qi][j * 4 + 0] += pr[qi] * v.x;
                    acc[qi][j * 4 + 1] += pr[qi] * v.y;
                    acc[qi][j * 4 + 2] += pr[qi] * v.z;
                    acc[qi][j * 4 + 3] += pr[qi] * v.w;
                }
            }
        }
    }

    // ---- epilogue: out = rs + alpha * O / l ----
    float av = alpha_p[0];
    #pragma unroll
    for (int qi = 0; qi < 4; ++qi) {
        float inv = av / lrun[qi];
        int m = q0 + ty + 16 * qi;
        #pragma unroll
        for (int j = 0; j < 4; ++j) {
            #pragma unroll
            for (int dd = 0; dd < 4; ++dd) {
                int d = tx * 4 + 64 * j + dd;
                size_t idx = ((size_t)(b * 256 + d)) * 4096 + m;
                out[idx] = rs[idx] + acc[qi][j * 4 + dd] * inv;
            }
        }
    }
}

// ---------------------------------------------------------------------------
extern "C" void kernel_launch(void* const* d_in, const int* in_sizes, int n_in,
                              void* d_out, int out_size, void* d_ws, size_t ws_size,
                              hipStream_t stream)
{
    const float* clip  = (const float*)d_in[0]; // [8,768,24,24]
    const float* rsf   = (const float*)d_in[1]; // [8,256,64,64]
    const float* gamma = (const float*)d_in[2]; // [768]
    const float* beta  = (const float*)d_in[3]; // [768]
    const float* W     = (const float*)d_in[4]; // [256,768]
    const float* bias  = (const float*)d_in[5]; // [256]
    const float* alpha = (const float*)d_in[6]; // [1]
    float* out  = (float*)d_out;                // [8,256,64,64]
    float* proj = (float*)d_ws;                 // [8,576,256] fp32 = 4.7 MB

    hipLaunchKernelGGL(ln_proj_kernel, dim3(144), dim3(256), 0, stream,
                       clip, gamma, beta, W, bias, proj);
    hipLaunchKernelGGL(attn_kernel, dim3(512), dim3(256), 0, stream,
                       proj, rsf, alpha, out);
}

// Round 2
// 175.569 us; speedup vs baseline: 2.6775x; 2.6775x over previous
//
#include <hip/hip_runtime.h>
#include <hip/hip_bf16.h>

#define EPSF 1e-5f

typedef short short8 __attribute__((ext_vector_type(8)));
typedef short short4v __attribute__((ext_vector_type(4)));
typedef float f32x4 __attribute__((ext_vector_type(4)));

__device__ __forceinline__ float dot4(float4 a, float4 b) {
    return a.x*b.x + a.y*b.y + a.z*b.z + a.w*b.w;
}

__device__ __forceinline__ short f2bf(float x) {
    __hip_bfloat16 h = __float2bfloat16(x);
    return reinterpret_cast<short&>(h);
}

// ---------------------------------------------------------------------------
// Kernel 1: fused LayerNorm + projection -> bf16 proj [B,576,256]
// ---------------------------------------------------------------------------
__global__ __launch_bounds__(256) void ln_proj_kernel(
    const float* __restrict__ clip,
    const float* __restrict__ gamma,
    const float* __restrict__ beta,
    const float* __restrict__ W,      // [256, 768]
    const float* __restrict__ bias,   // [256]
    short* __restrict__ proj)         // [B, 576, 256] bf16 bits
{
    __shared__ float xs[32][772];
    __shared__ float red1[8][32];
    __shared__ float red2[8][32];
    __shared__ float mu_s[32], rs_s[32];

    const int tid = threadIdx.x;
    const int b  = blockIdx.x / 18;
    const int n0 = (blockIdx.x % 18) * 32;
    const int nl = tid & 31;
    const int cg = tid >> 5;

    const float* cf = clip + (size_t)b * 768 * 576;

    float s1 = 0.f, s2 = 0.f;
    #pragma unroll 4
    for (int i = 0; i < 96; ++i) {
        int c = cg + (i << 3);
        float v = cf[c * 576 + n0 + nl];
        xs[nl][c] = v;
        s1 += v; s2 += v * v;
    }
    red1[cg][nl] = s1;
    red2[cg][nl] = s2;
    __syncthreads();
    if (tid < 32) {
        float a = 0.f, q = 0.f;
        #pragma unroll
        for (int g = 0; g < 8; ++g) { a += red1[g][tid]; q += red2[g][tid]; }
        float mu  = a * (1.f / 768.f);
        float var = q * (1.f / 768.f) - mu * mu;
        mu_s[tid] = mu;
        rs_s[tid] = rsqrtf(var + EPSF);
    }
    __syncthreads();
    {
        float mu = mu_s[nl], rsg = rs_s[nl];
        #pragma unroll 4
        for (int i = 0; i < 96; ++i) {
            int c = cg + (i << 3);
            xs[nl][c] = (xs[nl][c] - mu) * rsg * gamma[c] + beta[c];
        }
    }
    __syncthreads();

    const int dg = tid & 127;
    const int ng = tid >> 7;
    const int d0 = dg * 2, d1 = d0 + 1;
    const float* w0 = W + (size_t)d0 * 768;
    const float* w1 = W + (size_t)d1 * 768;

    float acc0[16], acc1[16];
    #pragma unroll
    for (int j = 0; j < 16; ++j) { acc0[j] = 0.f; acc1[j] = 0.f; }

    for (int k = 0; k < 768; k += 4) {
        float4 a  = *reinterpret_cast<const float4*>(w0 + k);
        float4 b4 = *reinterpret_cast<const float4*>(w1 + k);
        #pragma unroll
        for (int j = 0; j < 16; ++j) {
            float4 x = *reinterpret_cast<const float4*>(&xs[ng * 16 + j][k]);
            acc0[j] += dot4(x, a);
            acc1[j] += dot4(x, b4);
        }
    }

    float bb0 = bias[d0], bb1 = bias[d1];
    #pragma unroll
    for (int j = 0; j < 16; ++j) {
        int n = n0 + ng * 16 + j;
        unsigned int pk = (unsigned int)(unsigned short)f2bf(acc0[j] + bb0)
                        | ((unsigned int)(unsigned short)f2bf(acc1[j] + bb1) << 16);
        *reinterpret_cast<unsigned int*>(proj + ((size_t)b * 576 + n) * 256 + d0) = pk;
    }
}

// ---------------------------------------------------------------------------
// Kernel 2: MFMA flash attention.
// Q = rs [4096,256] (bf16 frags in regs), K = V = proj bf16 [576,256].
// Block = 256 thr (4 waves x 32 q-rows), grid = 8 b x 32 qtiles = 256.
// Swapped QK^T: S^T = mfma(K, Q) -> lane-local softmax over k.
// PV: O^T = mfma(V^T, P^T).
// ---------------------------------------------------------------------------
__global__ __launch_bounds__(256, 2) void attn_kernel(
    const short* __restrict__ Kbf,     // [B,576,256] bf16 bits
    const float* __restrict__ rs,      // [B,256,4096]
    const float* __restrict__ alpha_p,
    float* __restrict__ out)           // [B,256,4096]
{
    __shared__ union SMU {
        short q[64][264];                                   // Q staging (phase 0)
        struct { short K[32][264]; short VT[256][40]; } kv; // per-chunk K + V^T
        float ot[128][65];                                  // epilogue transpose
    } sm;
    __shared__ short P[4][32][40];                          // per-wave P tile

    const int tid = threadIdx.x;
    const int b   = blockIdx.x >> 5;
    const int q0  = (blockIdx.x & 31) << 7;
    const int w   = tid >> 6;
    const int l   = tid & 63;
    const int l15 = l & 15;
    const int g   = l >> 4;

    // ---- Phase 0: build Q fragments (2 q-subtiles x 8 d-chunks) ----
    short8 qf[2][8];
    for (int h = 0; h < 2; ++h) {
        __syncthreads();
        {
            int ml = tid & 63, dr = tid >> 6;
            const float* rp = rs + (size_t)b * 256 * 4096 + q0 + h * 64 + ml;
            for (int i = 0; i < 64; ++i) {
                int d = i * 4 + dr;
                sm.q[ml][d] = f2bf(rp[(size_t)d * 4096]);
            }
        }
        __syncthreads();
        if ((w >> 1) == h) {
            int rbase = 32 * (w & 1) + l15;
            #pragma unroll
            for (int qt = 0; qt < 2; ++qt)
                #pragma unroll
                for (int dc = 0; dc < 8; ++dc)
                    qf[qt][dc] = *reinterpret_cast<const short8*>(
                        &sm.q[rbase + 16 * qt][32 * dc + 8 * g]);
        }
    }

    f32x4 acc[2][16];
    #pragma unroll
    for (int qt = 0; qt < 2; ++qt)
        #pragma unroll
        for (int dt = 0; dt < 16; ++dt)
            acc[qt][dt] = f32x4{0.f, 0.f, 0.f, 0.f};
    float mrun[2] = {-1e30f, -1e30f};
    float lrun[2] = {0.f, 0.f};

    const short* kbase = Kbf + (size_t)b * 576 * 256;

    for (int kc = 0; kc < 18; ++kc) {
        __syncthreads();
        // ---- stage K [32][264] and V^T [256][40] ----
        {
            int r = tid >> 5, c = tid & 31;
            const short* src = kbase + (size_t)(kc * 32) * 256;
            #pragma unroll
            for (int i = 0; i < 4; ++i) {
                int k = i * 8 + r;
                *reinterpret_cast<short8*>(&sm.kv.K[k][c * 8]) =
                    *reinterpret_cast<const short8*>(src + k * 256 + c * 8);
            }
            const short* vsrc = src + tid;
            #pragma unroll
            for (int i = 0; i < 8; ++i) {
                short4v vv;
                vv.x = vsrc[(4 * i + 0) * 256];
                vv.y = vsrc[(4 * i + 1) * 256];
                vv.z = vsrc[(4 * i + 2) * 256];
                vv.w = vsrc[(4 * i + 3) * 256];
                *reinterpret_cast<short4v*>(&sm.kv.VT[tid][4 * i]) = vv;
            }
        }
        __syncthreads();

        // ---- S^T = K . Q^T  (tiles: kt x qt) ----
        f32x4 s[2][2];
        s[0][0] = f32x4{0.f,0.f,0.f,0.f}; s[0][1] = f32x4{0.f,0.f,0.f,0.f};
        s[1][0] = f32x4{0.f,0.f,0.f,0.f}; s[1][1] = f32x4{0.f,0.f,0.f,0.f};
        #pragma unroll
        for (int dc = 0; dc < 8; ++dc) {
            short8 kf0 = *reinterpret_cast<const short8*>(&sm.kv.K[l15][32 * dc + 8 * g]);
            short8 kf1 = *reinterpret_cast<const short8*>(&sm.kv.K[16 + l15][32 * dc + 8 * g]);
            s[0][0] = __builtin_amdgcn_mfma_f32_16x16x32_bf16(kf0, qf[0][dc], s[0][0], 0, 0, 0);
            s[1][0] = __builtin_amdgcn_mfma_f32_16x16x32_bf16(kf1, qf[0][dc], s[1][0], 0, 0, 0);
            s[0][1] = __builtin_amdgcn_mfma_f32_16x16x32_bf16(kf0, qf[1][dc], s[0][1], 0, 0, 0);
            s[1][1] = __builtin_amdgcn_mfma_f32_16x16x32_bf16(kf1, qf[1][dc], s[1][1], 0, 0, 0);
        }

        // ---- online softmax (per q-subtile); k = 16*kt + 4*g + r, q = l15 ----
        #pragma unroll
        for (int qt = 0; qt < 2; ++qt) {
            float p[8];
            #pragma unroll
            for (int j = 0; j < 4; ++j) { p[j] = s[0][qt][j]; p[4 + j] = s[1][qt][j]; }
            float pm = p[0];
            #pragma unroll
            for (int j = 1; j < 8; ++j) pm = fmaxf(pm, p[j]);
            pm = fmaxf(pm, __shfl_xor(pm, 16));
            pm = fmaxf(pm, __shfl_xor(pm, 32));
            if (!__all(pm - mrun[qt] <= 8.f)) {       // defer-max (T13)
                float mnew = fmaxf(mrun[qt], pm);
                float sc = __expf(mrun[qt] - mnew);
                lrun[qt] *= sc;
                #pragma unroll
                for (int dt = 0; dt < 16; ++dt) {
                    acc[qt][dt][0] *= sc; acc[qt][dt][1] *= sc;
                    acc[qt][dt][2] *= sc; acc[qt][dt][3] *= sc;
                }
                mrun[qt] = mnew;
            }
            float rsum = 0.f;
            #pragma unroll
            for (int j = 0; j < 8; ++j) { p[j] = __expf(p[j] - mrun[qt]); rsum += p[j]; }
            rsum += __shfl_xor(rsum, 16);
            rsum += __shfl_xor(rsum, 32);
            lrun[qt] += rsum;
            short4v p0, p1;
            p0.x = f2bf(p[0]); p0.y = f2bf(p[1]); p0.z = f2bf(p[2]); p0.w = f2bf(p[3]);
            p1.x = f2bf(p[4]); p1.y = f2bf(p[5]); p1.z = f2bf(p[6]); p1.w = f2bf(p[7]);
            *reinterpret_cast<short4v*>(&P[w][16 * qt + l15][4 * g]) = p0;
            *reinterpret_cast<short4v*>(&P[w][16 * qt + l15][16 + 4 * g]) = p1;
        }

        // ---- O^T += V^T . P^T ----
        short8 pf0 = *reinterpret_cast<const short8*>(&P[w][l15][8 * g]);
        short8 pf1 = *reinterpret_cast<const short8*>(&P[w][16 + l15][8 * g]);
        #pragma unroll
        for (int dt = 0; dt < 16; ++dt) {
            short8 vf = *reinterpret_cast<const short8*>(&sm.kv.VT[16 * dt + l15][8 * g]);
            acc[0][dt] = __builtin_amdgcn_mfma_f32_16x16x32_bf16(vf, pf0, acc[0][dt], 0, 0, 0);
            acc[1][dt] = __builtin_amdgcn_mfma_f32_16x16x32_bf16(vf, pf1, acc[1][dt], 0, 0, 0);
        }
    }

    // ---- epilogue: transpose O via LDS, out = rs + alpha * O / l ----
    float av = alpha_p[0];
    float inv0 = av / lrun[0], inv1 = av / lrun[1];
    const float* rp = rs + (size_t)b * 256 * 4096;
    float* op = out + (size_t)b * 256 * 4096;

    for (int sl = 0; sl < 4; ++sl) {
        __syncthreads();
        #pragma unroll
        for (int dt2 = 0; dt2 < 4; ++dt2) {
            int dt = sl * 4 + dt2;
            #pragma unroll
            for (int r = 0; r < 4; ++r) {
                sm.ot[32 * w + l15][16 * dt2 + 4 * g + r]      = acc[0][dt][r] * inv0;
                sm.ot[32 * w + 16 + l15][16 * dt2 + 4 * g + r] = acc[1][dt][r] * inv1;
            }
        }
        __syncthreads();
        int ml = tid & 127, dh = tid >> 7;
        #pragma unroll 4
        for (int i = 0; i < 32; ++i) {
            int dloc = 2 * i + dh;
            int d = sl * 64 + dloc;
            size_t idx = (size_t)d * 4096 + q0 + ml;
            op[idx] = rp[idx] + sm.ot[ml][dloc];
        }
    }
}

// ---------------------------------------------------------------------------
extern "C" void kernel_launch(void* const* d_in, const int* in_sizes, int n_in,
                              void* d_out, int out_size, void* d_ws, size_t ws_size,
                              hipStream_t stream)
{
    const float* clip  = (const float*)d_in[0]; // [8,768,24,24]
    const float* rsf   = (const float*)d_in[1]; // [8,256,64,64]
    const float* gamma = (const float*)d_in[2]; // [768]
    const float* beta  = (const float*)d_in[3]; // [768]
    const float* W     = (const float*)d_in[4]; // [256,768]
    const float* bias  = (const float*)d_in[5]; // [256]
    const float* alpha = (const float*)d_in[6]; // [1]
    float* out  = (float*)d_out;                // [8,256,64,64]
    short* proj = (short*)d_ws;                 // [8,576,256] bf16 = 2.36 MB

    hipLaunchKernelGGL(ln_proj_kernel, dim3(144), dim3(256), 0, stream,
                       clip, gamma, beta, W, bias, proj);
    hipLaunchKernelGGL(attn_kernel, dim3(256), dim3(256), 0, stream,
                       proj, rsf, alpha, out);
}

// Round 3
// 89.210 us; speedup vs baseline: 5.2694x; 1.9680x over previous
//
#include <hip/hip_runtime.h>
#include <hip/hip_bf16.h>

#define EPSF 1e-5f

typedef short short8 __attribute__((ext_vector_type(8)));
typedef short short4v __attribute__((ext_vector_type(4)));
typedef float f32x4 __attribute__((ext_vector_type(4)));

__device__ __forceinline__ short f2bf(float x) {
    __hip_bfloat16 h = __float2bfloat16(x);
    return reinterpret_cast<short&>(h);
}
__device__ __forceinline__ float bf2f(short s) {
    __hip_bfloat16 h = reinterpret_cast<__hip_bfloat16&>(s);
    return __bfloat162float(h);
}

// ---------------------------------------------------------------------------
// Kernel 0: pack W [256,768] f32 into hi/lo bf16 MFMA B-fragment order.
// Wp[((nt*24+kt)*64 + lane)*8 + j] = W[16*nt + (lane&15)][32*kt + 8*(lane>>4) + j]
// Grid 96 x 256.
// ---------------------------------------------------------------------------
__global__ __launch_bounds__(256) void w_pack_kernel(
    const float* __restrict__ W,
    short* __restrict__ Wp_hi,
    short* __restrict__ Wp_lo)
{
    int t = blockIdx.x * 256 + threadIdx.x;   // 0..24575
    int d    = t / 96;
    int kidx = t % 96;
    int k0   = kidx * 8;
    int nt = d >> 4, l15 = d & 15;
    int kt = kidx >> 2, g = kidx & 3;
    size_t dst = ((size_t)((nt * 24 + kt) * 64 + g * 16 + l15)) * 8;
    const float* src = W + (size_t)d * 768 + k0;
    #pragma unroll
    for (int j = 0; j < 8; ++j) {
        float w = src[j];
        short h = f2bf(w);
        short l = f2bf(w - bf2f(h));
        Wp_hi[dst + j] = h;
        Wp_lo[dst + j] = l;
    }
}

// ---------------------------------------------------------------------------
// Kernel 1: fused LayerNorm + MFMA projection (hi/lo split, ~fp32 accurate)
// clip [B,768,24,24] -> proj bf16 [B,576,256]. Grid 288 (16 tokens/block).
// ---------------------------------------------------------------------------
__global__ __launch_bounds__(256) void ln_proj_kernel(
    const float* __restrict__ clip,
    const float* __restrict__ gamma,
    const float* __restrict__ beta,
    const short* __restrict__ Wp_hi,
    const short* __restrict__ Wp_lo,
    const float* __restrict__ bias,
    short* __restrict__ proj)
{
    __shared__ short xh[16][776];    // 24.25 KB, row stride 97*16B
    __shared__ short xl[16][776];
    __shared__ float redA[4][16];
    __shared__ float redB[4][16];
    __shared__ float muS[16], rsS[16];

    const int tid = threadIdx.x;
    const int b  = blockIdx.x / 36;
    const int n0 = (blockIdx.x % 36) * 16;
    const int nl = tid & 15;
    const int cg = tid >> 4;         // 0..15
    const int w  = tid >> 6;
    const int l  = tid & 63;
    const int l15 = l & 15;
    const int g  = l >> 4;

    const float* base = clip + (size_t)b * 768 * 576 + n0 + nl;

    // ---- Phase A: LN stats ----
    float s1 = 0.f, s2 = 0.f;
    #pragma unroll 4
    for (int i = 0; i < 48; ++i) {
        int c = cg + 16 * i;
        float v = base[(size_t)c * 576];
        s1 += v; s2 += v * v;
    }
    s1 += __shfl_xor(s1, 16); s2 += __shfl_xor(s2, 16);
    s1 += __shfl_xor(s1, 32); s2 += __shfl_xor(s2, 32);
    if (g == 0) { redA[w][l15] = s1; redB[w][l15] = s2; }
    __syncthreads();
    if (tid < 16) {
        float a = redA[0][tid] + redA[1][tid] + redA[2][tid] + redA[3][tid];
        float q = redB[0][tid] + redB[1][tid] + redB[2][tid] + redB[3][tid];
        float mu = a * (1.f / 768.f);
        float var = q * (1.f / 768.f) - mu * mu;
        muS[tid] = mu;
        rsS[tid] = rsqrtf(var + EPSF);
    }
    __syncthreads();

    // ---- Phase B: normalize -> hi/lo bf16 into LDS (re-read, L2-hot) ----
    {
        float mu = muS[nl], rsg = rsS[nl];
        #pragma unroll 4
        for (int i = 0; i < 48; ++i) {
            int c = cg + 16 * i;
            float v = base[(size_t)c * 576];
            float y = (v - mu) * rsg * gamma[c] + beta[c];
            short h = f2bf(y);
            xh[nl][c] = h;
            xl[nl][c] = f2bf(y - bf2f(h));
        }
    }
    __syncthreads();

    // ---- Phase C: MFMA, wave w covers d in [64w, 64w+64) ----
    f32x4 acc[4];
    #pragma unroll
    for (int j = 0; j < 4; ++j) acc[j] = f32x4{0.f, 0.f, 0.f, 0.f};

    for (int kt = 0; kt < 24; ++kt) {
        short8 ah = *reinterpret_cast<const short8*>(&xh[l15][32 * kt + 8 * g]);
        short8 al = *reinterpret_cast<const short8*>(&xl[l15][32 * kt + 8 * g]);
        #pragma unroll
        for (int j = 0; j < 4; ++j) {
            int nt = 4 * w + j;
            size_t off = ((size_t)((nt * 24 + kt) * 64 + l)) * 8;
            short8 bh = *reinterpret_cast<const short8*>(Wp_hi + off);
            short8 bl = *reinterpret_cast<const short8*>(Wp_lo + off);
            acc[j] = __builtin_amdgcn_mfma_f32_16x16x32_bf16(ah, bh, acc[j], 0, 0, 0);
            acc[j] = __builtin_amdgcn_mfma_f32_16x16x32_bf16(al, bh, acc[j], 0, 0, 0);
            acc[j] = __builtin_amdgcn_mfma_f32_16x16x32_bf16(ah, bl, acc[j], 0, 0, 0);
        }
    }

    // ---- store: lane holds tokens 4g+r, d = 16*nt + l15 ----
    #pragma unroll
    for (int j = 0; j < 4; ++j) {
        int d = 16 * (4 * w + j) + l15;
        float bb = bias[d];
        #pragma unroll
        for (int r = 0; r < 4; ++r) {
            int tok = 4 * g + r;
            proj[((size_t)(b * 576 + n0 + tok)) * 256 + d] = f2bf(acc[j][r] + bb);
        }
    }
}

// ---------------------------------------------------------------------------
// Kernel 2: MFMA flash attention. Grid 512 = 8 b x 64 q-tiles of 64 rows.
// 4 waves x 16 q each. Q frags direct from global; K/VT staged per 64-kv chunk.
// ---------------------------------------------------------------------------
__global__ __launch_bounds__(256, 2) void attn_kernel(
    const short* __restrict__ proj,    // [B,576,256] bf16
    const float* __restrict__ rs,      // [B,256,4096]
    const float* __restrict__ alpha_p,
    float* __restrict__ out)           // [B,256,4096]
{
    __shared__ short Ks[64][264];      // 33.8 KB, row = 33*16B
    __shared__ short VTs[256][72];     // 36.9 KB, row = 9*16B  (VT[d][kv])
    __shared__ short Ps[4][16][72];    // 9.2 KB per-wave P[q][kv]

    const int tid = threadIdx.x;
    const int b  = blockIdx.x >> 6;
    const int q0 = (blockIdx.x & 63) << 6;
    const int w   = tid >> 6;
    const int l   = tid & 63;
    const int l15 = l & 15;
    const int g   = l >> 4;

    const short* kbase = proj + (size_t)b * 576 * 256;
    const float* rbase = rs + (size_t)b * 256 * 4096;
    const int qg = q0 + 16 * w + l15;   // this lane's q column

    // ---- build Q fragments direct from global (coalesced 64B segments) ----
    short8 qf[8];
    #pragma unroll
    for (int dc = 0; dc < 8; ++dc) {
        short8 v;
        #pragma unroll
        for (int j = 0; j < 8; ++j) {
            int d = 32 * dc + 8 * g + j;
            v[j] = f2bf(rbase[(size_t)d * 4096 + qg]);
        }
        qf[dc] = v;
    }

    f32x4 acc[16];
    #pragma unroll
    for (int dt = 0; dt < 16; ++dt) acc[dt] = f32x4{0.f, 0.f, 0.f, 0.f};
    float mrun = -1e30f, lrun = 0.f;

    const int kr = tid >> 5, kc5 = tid & 31;

    for (int kc = 0; kc < 9; ++kc) {
        __syncthreads();
        // ---- stage K [64][256] (b128 in/out) ----
        {
            const short* src = kbase + (size_t)(kc * 64) * 256;
            #pragma unroll
            for (int i = 0; i < 8; ++i) {
                int row = 8 * i + kr;
                *reinterpret_cast<short8*>(&Ks[row][kc5 * 8]) =
                    *reinterpret_cast<const short8*>(src + row * 256 + kc5 * 8);
            }
            // ---- stage VT[d][kv]: pack 8 kv per b128 write ----
            const short* vsrc = src + tid;
            #pragma unroll
            for (int i = 0; i < 8; ++i) {
                short8 v;
                #pragma unroll
                for (int j = 0; j < 8; ++j) v[j] = vsrc[(8 * i + j) * 256];
                *reinterpret_cast<short8*>(&VTs[tid][8 * i]) = v;
            }
        }
        __syncthreads();

        // ---- S^T = K . Q^T : 4 kv-tiles x 8 d-chunks ----
        f32x4 s[4];
        #pragma unroll
        for (int kt = 0; kt < 4; ++kt) s[kt] = f32x4{0.f, 0.f, 0.f, 0.f};
        #pragma unroll
        for (int dc = 0; dc < 8; ++dc) {
            #pragma unroll
            for (int kt = 0; kt < 4; ++kt) {
                short8 kf = *reinterpret_cast<const short8*>(&Ks[16 * kt + l15][32 * dc + 8 * g]);
                s[kt] = __builtin_amdgcn_mfma_f32_16x16x32_bf16(kf, qf[dc], s[kt], 0, 0, 0);
            }
        }

        // ---- online softmax; lane holds kv = 16*kt + 4*g + r for q = l15 ----
        float p[16];
        #pragma unroll
        for (int kt = 0; kt < 4; ++kt)
            #pragma unroll
            for (int r = 0; r < 4; ++r) p[4 * kt + r] = s[kt][r];
        float pm = p[0];
        #pragma unroll
        for (int j = 1; j < 16; ++j) pm = fmaxf(pm, p[j]);
        pm = fmaxf(pm, __shfl_xor(pm, 16));
        pm = fmaxf(pm, __shfl_xor(pm, 32));
        if (!__all(pm - mrun <= 8.f)) {            // defer-max (T13)
            float mnew = fmaxf(mrun, pm);
            float sc = __expf(mrun - mnew);
            lrun *= sc;
            #pragma unroll
            for (int dt = 0; dt < 16; ++dt) {
                acc[dt][0] *= sc; acc[dt][1] *= sc;
                acc[dt][2] *= sc; acc[dt][3] *= sc;
            }
            mrun = mnew;
        }
        float rsum = 0.f;
        #pragma unroll
        for (int j = 0; j < 16; ++j) { p[j] = __expf(p[j] - mrun); rsum += p[j]; }
        rsum += __shfl_xor(rsum, 16);
        rsum += __shfl_xor(rsum, 32);
        lrun += rsum;
        #pragma unroll
        for (int kt = 0; kt < 4; ++kt) {
            short4v pv;
            pv.x = f2bf(p[4 * kt + 0]); pv.y = f2bf(p[4 * kt + 1]);
            pv.z = f2bf(p[4 * kt + 2]); pv.w = f2bf(p[4 * kt + 3]);
            *reinterpret_cast<short4v*>(&Ps[w][l15][16 * kt + 4 * g]) = pv;
        }

        // ---- O^T += V^T . P^T ----
        short8 pf0 = *reinterpret_cast<const short8*>(&Ps[w][l15][8 * g]);
        short8 pf1 = *reinterpret_cast<const short8*>(&Ps[w][l15][32 + 8 * g]);
        #pragma unroll
        for (int dt = 0; dt < 16; ++dt) {
            short8 vf0 = *reinterpret_cast<const short8*>(&VTs[16 * dt + l15][8 * g]);
            short8 vf1 = *reinterpret_cast<const short8*>(&VTs[16 * dt + l15][32 + 8 * g]);
            acc[dt] = __builtin_amdgcn_mfma_f32_16x16x32_bf16(vf0, pf0, acc[dt], 0, 0, 0);
            acc[dt] = __builtin_amdgcn_mfma_f32_16x16x32_bf16(vf1, pf1, acc[dt], 0, 0, 0);
        }
    }

    // ---- epilogue: direct stores; lane holds d = 16*dt+4*g+r, q = qg ----
    float inv = alpha_p[0] / lrun;
    float* obase = out + (size_t)b * 256 * 4096;
    #pragma unroll
    for (int dt = 0; dt < 16; ++dt) {
        #pragma unroll
        for (int r = 0; r < 4; ++r) {
            int d = 16 * dt + 4 * g + r;
            size_t idx = (size_t)d * 4096 + qg;
            obase[idx] = rbase[idx] + acc[dt][r] * inv;
        }
    }
}

// ---------------------------------------------------------------------------
extern "C" void kernel_launch(void* const* d_in, const int* in_sizes, int n_in,
                              void* d_out, int out_size, void* d_ws, size_t ws_size,
                              hipStream_t stream)
{
    const float* clip  = (const float*)d_in[0];
    const float* rsf   = (const float*)d_in[1];
    const float* gamma = (const float*)d_in[2];
    const float* beta  = (const float*)d_in[3];
    const float* W     = (const float*)d_in[4];
    const float* bias  = (const float*)d_in[5];
    const float* alpha = (const float*)d_in[6];
    float* out = (float*)d_out;

    char* ws = (char*)d_ws;
    short* Wp_hi = (short*)ws;                       // 384 KB
    short* Wp_lo = (short*)(ws + 393216);            // 384 KB
    short* proj  = (short*)(ws + 786432);            // 2.36 MB

    hipLaunchKernelGGL(w_pack_kernel, dim3(96), dim3(256), 0, stream, W, Wp_hi, Wp_lo);
    hipLaunchKernelGGL(ln_proj_kernel, dim3(288), dim3(256), 0, stream,
                       clip, gamma, beta, Wp_hi, Wp_lo, bias, proj);
    hipLaunchKernelGGL(attn_kernel, dim3(512), dim3(256), 0, stream,
                       proj, rsf, alpha, out);
}

// Round 4
// 86.052 us; speedup vs baseline: 5.4628x; 1.0367x over previous
//
#include <hip/hip_runtime.h>
#include <hip/hip_bf16.h>

#define EPSF 1e-5f

typedef short short8 __attribute__((ext_vector_type(8)));
typedef short short4v __attribute__((ext_vector_type(4)));
typedef float f32x4 __attribute__((ext_vector_type(4)));

__device__ __forceinline__ short f2bf(float x) {
    __hip_bfloat16 h = __float2bfloat16(x);
    return reinterpret_cast<short&>(h);
}
__device__ __forceinline__ float bf2f(short s) {
    __hip_bfloat16 h = reinterpret_cast<__hip_bfloat16&>(s);
    return __bfloat162float(h);
}

// ---------------------------------------------------------------------------
// Kernel 0: pack W [256,768] f32 -> hi/lo bf16 MFMA B-fragment order.
// Destination-linear: thread t writes Wp[8t..8t+8) (fully coalesced stores).
// Wp[((nt*24+kt)*64 + g*16 + l15)*8 + j] = W[16nt+l15][32kt+8g+j]
// ---------------------------------------------------------------------------
__global__ __launch_bounds__(256) void w_pack_kernel(
    const float* __restrict__ W,
    short* __restrict__ Wp_hi,
    short* __restrict__ Wp_lo)
{
    int t = blockIdx.x * 256 + threadIdx.x;   // 0..24575
    int l15 = t & 15;
    int g   = (t >> 4) & 3;
    int kt  = (t >> 6) % 24;
    int nt  = t / 1536;
    const float* src = W + (size_t)(16 * nt + l15) * 768 + 32 * kt + 8 * g;
    short8 h8, l8;
    #pragma unroll
    for (int j = 0; j < 8; ++j) {
        float w = src[j];
        short h = f2bf(w);
        h8[j] = h;
        l8[j] = f2bf(w - bf2f(h));
    }
    *reinterpret_cast<short8*>(Wp_hi + (size_t)t * 8) = h8;
    *reinterpret_cast<short8*>(Wp_lo + (size_t)t * 8) = l8;
}

// ---------------------------------------------------------------------------
// Kernel 1: fused LayerNorm + MFMA projection (hi/lo split, ~fp32 accurate)
// Single global pass: clip staged in registers. Grid 288 (16 tokens/block).
// ---------------------------------------------------------------------------
__global__ __launch_bounds__(256) void ln_proj_kernel(
    const float* __restrict__ clip,
    const float* __restrict__ gamma,
    const float* __restrict__ beta,
    const short* __restrict__ Wp_hi,
    const short* __restrict__ Wp_lo,
    const float* __restrict__ bias,
    short* __restrict__ proj)
{
    __shared__ short xh[16][776];
    __shared__ short xl[16][776];
    __shared__ float redA[4][16];
    __shared__ float redB[4][16];
    __shared__ float muS[16], rsS[16];

    const int tid = threadIdx.x;
    const int b  = blockIdx.x / 36;
    const int n0 = (blockIdx.x % 36) * 16;
    const int nl = tid & 15;
    const int cg = tid >> 4;         // 0..15
    const int w  = tid >> 6;
    const int l  = tid & 63;
    const int l15 = l & 15;
    const int g  = l >> 4;

    const float* base = clip + (size_t)b * 768 * 576 + n0 + nl;

    // ---- Phase A: single global read into regs + LN stats ----
    float x[48];
    float s1 = 0.f, s2 = 0.f;
    #pragma unroll
    for (int i = 0; i < 48; ++i) {
        x[i] = base[(size_t)(cg + 16 * i) * 576];
        s1 += x[i]; s2 += x[i] * x[i];
    }
    s1 += __shfl_xor(s1, 16); s2 += __shfl_xor(s2, 16);
    s1 += __shfl_xor(s1, 32); s2 += __shfl_xor(s2, 32);
    if (g == 0) { redA[w][l15] = s1; redB[w][l15] = s2; }
    __syncthreads();
    if (tid < 16) {
        float a = redA[0][tid] + redA[1][tid] + redA[2][tid] + redA[3][tid];
        float q = redB[0][tid] + redB[1][tid] + redB[2][tid] + redB[3][tid];
        float mu = a * (1.f / 768.f);
        float var = q * (1.f / 768.f) - mu * mu;
        muS[tid] = mu;
        rsS[tid] = rsqrtf(var + EPSF);
    }
    __syncthreads();

    // ---- Phase B: normalize regs -> hi/lo bf16 LDS ----
    {
        float mu = muS[nl], rsg = rsS[nl];
        #pragma unroll
        for (int i = 0; i < 48; ++i) {
            int c = cg + 16 * i;
            float y = (x[i] - mu) * rsg * gamma[c] + beta[c];
            short h = f2bf(y);
            xh[nl][c] = h;
            xl[nl][c] = f2bf(y - bf2f(h));
        }
    }
    __syncthreads();

    // ---- Phase C: MFMA, wave w covers d in [64w, 64w+64) ----
    f32x4 acc[4];
    #pragma unroll
    for (int j = 0; j < 4; ++j) acc[j] = f32x4{0.f, 0.f, 0.f, 0.f};

    for (int kt = 0; kt < 24; ++kt) {
        short8 ah = *reinterpret_cast<const short8*>(&xh[l15][32 * kt + 8 * g]);
        short8 al = *reinterpret_cast<const short8*>(&xl[l15][32 * kt + 8 * g]);
        #pragma unroll
        for (int j = 0; j < 4; ++j) {
            int nt = 4 * w + j;
            size_t off = ((size_t)((nt * 24 + kt) * 64 + l)) * 8;
            short8 bh = *reinterpret_cast<const short8*>(Wp_hi + off);
            short8 bl = *reinterpret_cast<const short8*>(Wp_lo + off);
            acc[j] = __builtin_amdgcn_mfma_f32_16x16x32_bf16(ah, bh, acc[j], 0, 0, 0);
            acc[j] = __builtin_amdgcn_mfma_f32_16x16x32_bf16(al, bh, acc[j], 0, 0, 0);
            acc[j] = __builtin_amdgcn_mfma_f32_16x16x32_bf16(ah, bl, acc[j], 0, 0, 0);
        }
    }

    #pragma unroll
    for (int j = 0; j < 4; ++j) {
        int d = 16 * (4 * w + j) + l15;
        float bb = bias[d];
        #pragma unroll
        for (int r = 0; r < 4; ++r) {
            int tok = 4 * g + r;
            proj[((size_t)(b * 576 + n0 + tok)) * 256 + d] = f2bf(acc[j][r] + bb);
        }
    }
}

// ---------------------------------------------------------------------------
// Kernel 2: MFMA flash attention with T14 register prefetch pipeline.
// Grid 512 = 8 b x 64 q-tiles of 64 rows. 4 waves x 16 q each.
// ---------------------------------------------------------------------------
__global__ __launch_bounds__(256, 2) void attn_kernel(
    const short* __restrict__ proj,    // [B,576,256] bf16
    const float* __restrict__ rs,      // [B,256,4096]
    const float* __restrict__ alpha_p,
    float* __restrict__ out)           // [B,256,4096]
{
    __shared__ short Ks[64][264];      // 33.8 KB
    __shared__ short VTs[256][72];     // 36.9 KB (VT[d][kv])
    __shared__ short Ps[4][16][72];    // 9.2 KB per-wave P[q][kv]

    const int tid = threadIdx.x;
    const int b  = blockIdx.x >> 6;
    const int q0 = (blockIdx.x & 63) << 6;
    const int w   = tid >> 6;
    const int l   = tid & 63;
    const int l15 = l & 15;
    const int g   = l >> 4;

    const short* kbase = proj + (size_t)b * 576 * 256;
    const float* rbase = rs + (size_t)b * 256 * 4096;
    const int qg = q0 + 16 * w + l15;

    // ---- Q fragments direct from global ----
    short8 qf[8];
    #pragma unroll
    for (int dc = 0; dc < 8; ++dc) {
        short8 v;
        #pragma unroll
        for (int j = 0; j < 8; ++j) {
            int d = 32 * dc + 8 * g + j;
            v[j] = f2bf(rbase[(size_t)d * 4096 + qg]);
        }
        qf[dc] = v;
    }

    f32x4 acc[16];
    #pragma unroll
    for (int dt = 0; dt < 16; ++dt) acc[dt] = f32x4{0.f, 0.f, 0.f, 0.f};
    float mrun = -1e30f, lrun = 0.f;

    const int kr = tid >> 5, kc5 = tid & 31;
    short8 kpre[8];
    short  vpre[64];

    // ---- prologue: prefetch + write chunk 0 ----
    {
        const short* src = kbase;
        #pragma unroll
        for (int i = 0; i < 8; ++i)
            kpre[i] = *reinterpret_cast<const short8*>(src + (8 * i + kr) * 256 + kc5 * 8);
        const short* vs = src + tid;
        #pragma unroll
        for (int i = 0; i < 64; ++i) vpre[i] = vs[i * 256];
    }
    #pragma unroll
    for (int i = 0; i < 8; ++i)
        *reinterpret_cast<short8*>(&Ks[8 * i + kr][kc5 * 8]) = kpre[i];
    #pragma unroll
    for (int i = 0; i < 8; ++i) {
        short8 v;
        #pragma unroll
        for (int j = 0; j < 8; ++j) v[j] = vpre[8 * i + j];
        *reinterpret_cast<short8*>(&VTs[tid][8 * i]) = v;
    }
    __syncthreads();

    for (int kc = 0; kc < 9; ++kc) {
        // ---- T14: issue next-chunk loads early ----
        if (kc < 8) {
            const short* src = kbase + (size_t)((kc + 1) * 64) * 256;
            #pragma unroll
            for (int i = 0; i < 8; ++i)
                kpre[i] = *reinterpret_cast<const short8*>(src + (8 * i + kr) * 256 + kc5 * 8);
            const short* vs = src + tid;
            #pragma unroll
            for (int i = 0; i < 64; ++i) vpre[i] = vs[i * 256];
        }

        // ---- S^T = K . Q^T ----
        f32x4 s[4];
        #pragma unroll
        for (int kt = 0; kt < 4; ++kt) s[kt] = f32x4{0.f, 0.f, 0.f, 0.f};
        __builtin_amdgcn_s_setprio(1);
        #pragma unroll
        for (int dc = 0; dc < 8; ++dc) {
            #pragma unroll
            for (int kt = 0; kt < 4; ++kt) {
                short8 kf = *reinterpret_cast<const short8*>(&Ks[16 * kt + l15][32 * dc + 8 * g]);
                s[kt] = __builtin_amdgcn_mfma_f32_16x16x32_bf16(kf, qf[dc], s[kt], 0, 0, 0);
            }
        }
        __builtin_amdgcn_s_setprio(0);

        // ---- online softmax; lane holds kv = 16*kt+4*g+r for q = l15 ----
        float p[16];
        #pragma unroll
        for (int kt = 0; kt < 4; ++kt)
            #pragma unroll
            for (int r = 0; r < 4; ++r) p[4 * kt + r] = s[kt][r];
        float pm = p[0];
        #pragma unroll
        for (int j = 1; j < 16; ++j) pm = fmaxf(pm, p[j]);
        pm = fmaxf(pm, __shfl_xor(pm, 16));
        pm = fmaxf(pm, __shfl_xor(pm, 32));
        if (!__all(pm - mrun <= 8.f)) {            // defer-max (T13)
            float mnew = fmaxf(mrun, pm);
            float sc = __expf(mrun - mnew);
            lrun *= sc;
            #pragma unroll
            for (int dt = 0; dt < 16; ++dt) {
                acc[dt][0] *= sc; acc[dt][1] *= sc;
                acc[dt][2] *= sc; acc[dt][3] *= sc;
            }
            mrun = mnew;
        }
        float rsum = 0.f;
        #pragma unroll
        for (int j = 0; j < 16; ++j) { p[j] = __expf(p[j] - mrun); rsum += p[j]; }
        rsum += __shfl_xor(rsum, 16);
        rsum += __shfl_xor(rsum, 32);
        lrun += rsum;
        #pragma unroll
        for (int kt = 0; kt < 4; ++kt) {
            short4v pv;
            pv.x = f2bf(p[4 * kt + 0]); pv.y = f2bf(p[4 * kt + 1]);
            pv.z = f2bf(p[4 * kt + 2]); pv.w = f2bf(p[4 * kt + 3]);
            *reinterpret_cast<short4v*>(&Ps[w][l15][16 * kt + 4 * g]) = pv;
        }

        // ---- O^T += V^T . P^T ----
        short8 pf0 = *reinterpret_cast<const short8*>(&Ps[w][l15][8 * g]);
        short8 pf1 = *reinterpret_cast<const short8*>(&Ps[w][l15][32 + 8 * g]);
        __builtin_amdgcn_s_setprio(1);
        #pragma unroll
        for (int dt = 0; dt < 16; ++dt) {
            short8 vf0 = *reinterpret_cast<const short8*>(&VTs[16 * dt + l15][8 * g]);
            short8 vf1 = *reinterpret_cast<const short8*>(&VTs[16 * dt + l15][32 + 8 * g]);
            acc[dt] = __builtin_amdgcn_mfma_f32_16x16x32_bf16(vf0, pf0, acc[dt], 0, 0, 0);
            acc[dt] = __builtin_amdgcn_mfma_f32_16x16x32_bf16(vf1, pf1, acc[dt], 0, 0, 0);
        }
        __builtin_amdgcn_s_setprio(0);

        __syncthreads();               // everyone done reading LDS chunk kc

        // ---- T14 write-late: regs -> LDS for chunk kc+1 ----
        if (kc < 8) {
            #pragma unroll
            for (int i = 0; i < 8; ++i)
                *reinterpret_cast<short8*>(&Ks[8 * i + kr][kc5 * 8]) = kpre[i];
            #pragma unroll
            for (int i = 0; i < 8; ++i) {
                short8 v;
                #pragma unroll
                for (int j = 0; j < 8; ++j) v[j] = vpre[8 * i + j];
                *reinterpret_cast<short8*>(&VTs[tid][8 * i]) = v;
            }
            __syncthreads();
        }
    }

    // ---- epilogue: direct stores ----
    float inv = alpha_p[0] / lrun;
    float* obase = out + (size_t)b * 256 * 4096;
    #pragma unroll
    for (int dt = 0; dt < 16; ++dt) {
        #pragma unroll
        for (int r = 0; r < 4; ++r) {
            int d = 16 * dt + 4 * g + r;
            size_t idx = (size_t)d * 4096 + qg;
            obase[idx] = rbase[idx] + acc[dt][r] * inv;
        }
    }
}

// ---------------------------------------------------------------------------
extern "C" void kernel_launch(void* const* d_in, const int* in_sizes, int n_in,
                              void* d_out, int out_size, void* d_ws, size_t ws_size,
                              hipStream_t stream)
{
    const float* clip  = (const float*)d_in[0];
    const float* rsf   = (const float*)d_in[1];
    const float* gamma = (const float*)d_in[2];
    const float* beta  = (const float*)d_in[3];
    const float* W     = (const float*)d_in[4];
    const float* bias  = (const float*)d_in[5];
    const float* alpha = (const float*)d_in[6];
    float* out = (float*)d_out;

    char* ws = (char*)d_ws;
    short* Wp_hi = (short*)ws;                       // 384 KB
    short* Wp_lo = (short*)(ws + 393216);            // 384 KB
    short* proj  = (short*)(ws + 786432);            // 2.36 MB

    hipLaunchKernelGGL(w_pack_kernel, dim3(96), dim3(256), 0, stream, W, Wp_hi, Wp_lo);
    hipLaunchKernelGGL(ln_proj_kernel, dim3(288), dim3(256), 0, stream,
                       clip, gamma, beta, Wp_hi, Wp_lo, bias, proj);
    hipLaunchKernelGGL(attn_kernel, dim3(512), dim3(256), 0, stream,
                       proj, rsf, alpha, out);
}